// Round 2
// baseline (240.361 us; speedup 1.0000x reference)
//
#include <hip/hip_runtime.h>

// Scaled dot-product attention, flash-style.
// fp32 global storage (per reference dtypes); bf16 MFMA compute; fp32 softmax.
// BH=32, S=2048, D=64, mask [2,S,S] additive (tiled bh%2).

constexpr int cBH = 32;
constexpr int cS  = 2048;
constexpr int cD  = 64;
constexpr int cQT = 64;   // q rows per block (4 waves x 16)
constexpr int cKT = 64;   // k cols per iteration
constexpr int cNW = 4;    // waves per block

typedef __bf16 bf16x8 __attribute__((ext_vector_type(8)));
typedef float  f32x4  __attribute__((ext_vector_type(4)));

__device__ __forceinline__ unsigned short bfbits(float f) {
    __bf16 h = (__bf16)f;                       // HW cvt, RNE
    return __builtin_bit_cast(unsigned short, h);
}
// swizzled V^T element index: row d (0..63), col kk (0..63).
// 8-element blocks along k stay contiguous (ds_read_b128) but the block slot
// is XORed with g(d) so transpose-writes and frag-reads are <=2-way conflicts.
__device__ __forceinline__ int vswz(int d, int kk) {
    int g = (d ^ (d >> 3)) & 7;
    return d * 64 + ((((kk >> 3) ^ g) & 7) << 3) + (kk & 7);
}

__global__ __launch_bounds__(256)
void sdpa_flash_kernel(const float* __restrict__ q,
                       const float* __restrict__ k,
                       const float* __restrict__ v,
                       const float* __restrict__ mask,
                       float* __restrict__ out)
{
    __shared__ unsigned short sK[cKT * 72];       // [kcol][d], stride 72 (pad)
    __shared__ unsigned short sV[cD * 64];        // V^T, swizzled
    __shared__ unsigned short sP[cNW][16 * 72];   // per-wave P scratch

    const int tid  = threadIdx.x;
    const int wv   = tid >> 6;
    const int lane = tid & 63;
    const int quad = lane >> 4;
    const int ln   = lane & 15;

    const int qb = blockIdx.x * cQT;
    const int bh = blockIdx.y;
    const int mb = bh & 1;            // mask batch = bh % 2

    // ---- Q fragments (A-operand), row qb + wv*16 + ln, kept in registers ----
    const int qrow = qb + wv * 16 + ln;
    bf16x8 aq[2];
    {
        const float* qp = q + (size_t)(bh * cS + qrow) * cD;
#pragma unroll
        for (int s = 0; s < 2; ++s) {
            __bf16 h[8];
#pragma unroll
            for (int j = 0; j < 8; ++j)
                h[j] = (__bf16)qp[s * 32 + quad * 8 + j];
            aq[s] = *reinterpret_cast<bf16x8*>(h);
        }
    }

    f32x4 acc[4];
    float mst[4], lst[4];
#pragma unroll
    for (int t = 0; t < 4; ++t) acc[t] = (f32x4){0.f, 0.f, 0.f, 0.f};
#pragma unroll
    for (int r = 0; r < 4; ++r) { mst[r] = -INFINITY; lst[r] = 0.f; }

    const float L2E = 1.4426950408889634f;
    // mask row base for this thread's 4 q-rows; cols indexed by kb + nt*16 + ln
    const float* mbase = mask + (size_t)mb * cS * cS
                              + (size_t)(qb + wv * 16 + quad * 4) * cS + ln;

    // staging coordinates: thread covers 16 consecutive d of one row
    const int skr = tid >> 2;            // 0..63
    const int sd0 = (tid & 3) << 4;      // 0,16,32,48

    for (int kt = 0; kt < cS / cKT; ++kt) {
        const int kb = kt * cKT;

        // ---- stage K (row-major, padded) and V^T (swizzled), fp32 -> bf16 ----
        {
            const float* kp = k + (size_t)(bh * cS + kb + skr) * cD + sd0;
            __bf16 hk[16];
#pragma unroll
            for (int j = 0; j < 16; ++j) hk[j] = (__bf16)kp[j];
            *reinterpret_cast<uint4*>(&sK[skr * 72 + sd0])     = reinterpret_cast<uint4*>(hk)[0];
            *reinterpret_cast<uint4*>(&sK[skr * 72 + sd0 + 8]) = reinterpret_cast<uint4*>(hk)[1];

            const float* vp = v + (size_t)(bh * cS + kb + skr) * cD + sd0;
#pragma unroll
            for (int j = 0; j < 16; ++j)
                sV[vswz(sd0 + j, skr)] = bfbits(vp[j]);
        }
        __syncthreads();

        // ---- S = Q K^T * scale + mask  (C-layout: row=quad*4+r, col=nt*16+ln) ----
        float sc[4][4];
#pragma unroll
        for (int nt = 0; nt < 4; ++nt) {
            f32x4 c = (f32x4){0.f, 0.f, 0.f, 0.f};
#pragma unroll
            for (int ks = 0; ks < 2; ++ks) {
                bf16x8 b = *reinterpret_cast<const bf16x8*>(
                    &sK[(nt * 16 + ln) * 72 + ks * 32 + quad * 8]);
                c = __builtin_amdgcn_mfma_f32_16x16x32_bf16(aq[ks], b, c, 0, 0, 0);
            }
#pragma unroll
            for (int r = 0; r < 4; ++r) {
                float mval = mbase[(size_t)r * cS + kb + nt * 16];
                sc[nt][r] = c[r] * 0.125f + mval;
            }
        }

        // ---- online softmax (each row lives on 16 lanes of one quad) ----
        float rmax[4];
#pragma unroll
        for (int r = 0; r < 4; ++r)
            rmax[r] = fmaxf(fmaxf(sc[0][r], sc[1][r]), fmaxf(sc[2][r], sc[3][r]));
#pragma unroll
        for (int off = 1; off < 16; off <<= 1)
#pragma unroll
            for (int r = 0; r < 4; ++r)
                rmax[r] = fmaxf(rmax[r], __shfl_xor(rmax[r], off, 64));

        float alpha[4];
#pragma unroll
        for (int r = 0; r < 4; ++r) {
            float mn = fmaxf(mst[r], rmax[r]);
            alpha[r] = __builtin_amdgcn_exp2f((mst[r] - mn) * L2E);
            mst[r] = mn;
        }
        float pv[4][4];
#pragma unroll
        for (int nt = 0; nt < 4; ++nt)
#pragma unroll
            for (int r = 0; r < 4; ++r)
                pv[nt][r] = __builtin_amdgcn_exp2f((sc[nt][r] - mst[r]) * L2E);
        float rsum[4];
#pragma unroll
        for (int r = 0; r < 4; ++r)
            rsum[r] = (pv[0][r] + pv[1][r]) + (pv[2][r] + pv[3][r]);
#pragma unroll
        for (int off = 1; off < 16; off <<= 1)
#pragma unroll
            for (int r = 0; r < 4; ++r)
                rsum[r] += __shfl_xor(rsum[r], off, 64);
#pragma unroll
        for (int r = 0; r < 4; ++r)
            lst[r] = lst[r] * alpha[r] + rsum[r];
#pragma unroll
        for (int t = 0; t < 4; ++t)
#pragma unroll
            for (int r = 0; r < 4; ++r)
                acc[t][r] *= alpha[r];

        // ---- P -> per-wave LDS (C-layout -> A-layout transform) ----
#pragma unroll
        for (int nt = 0; nt < 4; ++nt)
#pragma unroll
            for (int r = 0; r < 4; ++r)
                sP[wv][(quad * 4 + r) * 72 + nt * 16 + ln] = bfbits(pv[nt][r]);
        // same-wave DS ops: LDS unit processes them in order; no barrier needed

        // ---- O += P V ----
#pragma unroll
        for (int ks = 0; ks < 2; ++ks) {
            bf16x8 ap = *reinterpret_cast<const bf16x8*>(
                &sP[wv][ln * 72 + ks * 32 + quad * 8]);
            const int kk = ks * 32 + quad * 8;
#pragma unroll
            for (int dt = 0; dt < 4; ++dt) {
                bf16x8 bv = *reinterpret_cast<const bf16x8*>(&sV[vswz(dt * 16 + ln, kk)]);
                acc[dt] = __builtin_amdgcn_mfma_f32_16x16x32_bf16(ap, bv, acc[dt], 0, 0, 0);
            }
        }
        __syncthreads();   // protect sK/sV for next iteration
    }

    // ---- epilogue: O = acc / l ----
#pragma unroll
    for (int dt = 0; dt < 4; ++dt) {
#pragma unroll
        for (int r = 0; r < 4; ++r) {
            const int gq = qb + wv * 16 + quad * 4 + r;
            out[(size_t)(bh * cS + gq) * cD + dt * 16 + ln] = acc[dt][r] / lst[r];
        }
    }
}

extern "C" void kernel_launch(void* const* d_in, const int* in_sizes, int n_in,
                              void* d_out, int out_size, void* d_ws, size_t ws_size,
                              hipStream_t stream) {
    const float* q = (const float*)d_in[0];
    const float* k = (const float*)d_in[1];
    const float* v = (const float*)d_in[2];
    const float* m = (const float*)d_in[3];
    float* o = (float*)d_out;
    dim3 grid(cS / cQT, cBH);   // 32 q-tiles x 32 batch-heads = 1024 blocks
    sdpa_flash_kernel<<<grid, 256, 0, stream>>>(q, k, v, m, o);
}